// Round 1
// baseline (447.733 us; speedup 1.0000x reference)
//
#include <hip/hip_runtime.h>

// Channel self-attention, B=8 C=512 H=W=64 (N=4096), fp32 in/out.
//
// Decomposition (contraction over spatial N factors through Gram matrix):
//   G  = x x^T                      (B,C,C)  split-bf16 3-product MFMA
//   U  = wk G                       (B,C,C)  split x split
//   S  = wq U^T (BT) + rank-1 bias terms     split x split
//   attn = softmax_rows(S)
//   M  = attn wv                    single bf16
//   out = M x + (attn bv) 1^T       single bf16, Bt = xh^T
//
// Workspace usage ~131 MB.

typedef unsigned short u16;
typedef short v8s __attribute__((ext_vector_type(8)));
typedef float v4f __attribute__((ext_vector_type(4)));

#define B_ 8
#define C_ 512
#define N_ 4096

__device__ __forceinline__ u16 f2bf(float f) {
  unsigned int u = __builtin_bit_cast(unsigned int, f);
  u = u + 0x7fffu + ((u >> 16) & 1u);
  return (u16)(u >> 16);
}
__device__ __forceinline__ float bf2f(u16 h) {
  unsigned int u = ((unsigned int)h) << 16;
  return __builtin_bit_cast(float, u);
}
__device__ __forceinline__ void gld_lds16(const u16* g, u16* l) {
  __builtin_amdgcn_global_load_lds((__attribute__((address_space(1))) void*)(g),
                                   (__attribute__((address_space(3))) void*)(l),
                                   16, 0, 0);
}

// ---------------- BT-GEMM workhorse (m97 structure) ----------------
// D[m][n] = sum_k A[m][k] * Bt[n][k]; A: (128*gridY) x K row-major, Bt: (128*gridX) x K.
// SPLIT: A,B each have hi/lo bf16 halves; 3 MFMA products per tile (hh, hl, lh).
// EPI: 0 = fp32 store, 1 = split hi/lo bf16 store, 2 = bf16-hi store, 3 = fp32 + rowbias.
template <bool SPLIT, int EPI>
__global__ __launch_bounds__(256) void gemm_bt(
    const u16* __restrict__ Ah, const u16* __restrict__ Al, long long sA_,
    const u16* __restrict__ Bh, const u16* __restrict__ Bl, long long sB_,
    int K, int ldc,
    float* __restrict__ Cf, u16* __restrict__ Ch, u16* __restrict__ Cl,
    long long sC_, const float* __restrict__ rowbias) {
  __shared__ __attribute__((aligned(16))) u16 sA0[128 * 32];
  __shared__ __attribute__((aligned(16))) u16 sA1[128 * 32];
  __shared__ __attribute__((aligned(16))) u16 sB0[128 * 32];
  __shared__ __attribute__((aligned(16))) u16 sB1[128 * 32];
  int b = blockIdx.z;
  int tid = threadIdx.x, lane = tid & 63, w = tid >> 6;
  const u16* pAh = Ah + (size_t)b * sA_ + (size_t)blockIdx.y * 128 * K;
  const u16* pBh = Bh + (size_t)b * sB_ + (size_t)blockIdx.x * 128 * K;
  const u16* pAl = SPLIT ? (Al + (size_t)b * sA_ + (size_t)blockIdx.y * 128 * K) : pAh;
  const u16* pBl = SPLIT ? (Bl + (size_t)b * sB_ + (size_t)blockIdx.x * 128 * K) : pBh;
  int wr = (w >> 1) * 64, wc = (w & 1) * 64;
  v4f acc[4][4] = {};
  int srow_off = lane >> 2;     // 4 lanes per 64B row
  int scol = (lane & 3) * 8;    // 16B chunk within row (in shorts)

  for (int k0 = 0; k0 < K; k0 += 32) {
    if (SPLIT) {
      const u16* base = (w == 0) ? pAh : (w == 1) ? pAl : (w == 2) ? pBh : pBl;
      u16* lds = (w == 0) ? sA0 : (w == 1) ? sA1 : (w == 2) ? sB0 : sB1;
      for (int t = 0; t < 8; ++t)
        gld_lds16(base + (size_t)(t * 16 + srow_off) * K + k0 + scol, lds + t * 16 * 32);
    } else {
      const u16* base = (w < 2) ? pAh : pBh;
      u16* lds = (w < 2) ? sA0 : sB0;
      int o = (w & 1) * 4;
      for (int t = 0; t < 4; ++t) {
        int s = o + t;
        gld_lds16(base + (size_t)(s * 16 + srow_off) * K + k0 + scol, lds + s * 16 * 32);
      }
    }
    __syncthreads();
    int r = lane & 15, q = lane >> 4;
    v8s a0[4], a1[4], b0[4], b1[4];
    for (int mt = 0; mt < 4; ++mt) {
      int off = (wr + mt * 16 + r) * 32 + q * 8;
      a0[mt] = *(const v8s*)(const void*)(sA0 + off);
      if (SPLIT) a1[mt] = *(const v8s*)(const void*)(sA1 + off);
    }
    for (int nt = 0; nt < 4; ++nt) {
      int off = (wc + nt * 16 + r) * 32 + q * 8;
      b0[nt] = *(const v8s*)(const void*)(sB0 + off);
      if (SPLIT) b1[nt] = *(const v8s*)(const void*)(sB1 + off);
    }
    for (int mt = 0; mt < 4; ++mt)
      for (int nt = 0; nt < 4; ++nt) {
        acc[mt][nt] = __builtin_amdgcn_mfma_f32_16x16x32_bf16(a0[mt], b0[nt], acc[mt][nt], 0, 0, 0);
        if (SPLIT) {
          acc[mt][nt] = __builtin_amdgcn_mfma_f32_16x16x32_bf16(a0[mt], b1[nt], acc[mt][nt], 0, 0, 0);
          acc[mt][nt] = __builtin_amdgcn_mfma_f32_16x16x32_bf16(a1[mt], b0[nt], acc[mt][nt], 0, 0, 0);
        }
      }
    __syncthreads();
  }

  int r = lane & 15, q = lane >> 4;
  for (int mt = 0; mt < 4; ++mt)
    for (int nt = 0; nt < 4; ++nt) {
      int row0 = blockIdx.y * 128 + wr + mt * 16 + q * 4;
      int col = blockIdx.x * 128 + wc + nt * 16 + r;
      for (int e = 0; e < 4; ++e) {
        float vv = acc[mt][nt][e];
        size_t off = (size_t)b * sC_ + (size_t)(row0 + e) * ldc + col;
        if (EPI == 0) {
          Cf[off] = vv;
        } else if (EPI == 1) {
          u16 h = f2bf(vv);
          Ch[off] = h;
          Cl[off] = f2bf(vv - bf2f(h));
        } else if (EPI == 2) {
          Ch[off] = f2bf(vv);
        } else {
          Cf[off] = vv + rowbias[(size_t)b * C_ + row0 + e];
        }
      }
    }
}

// x (B,C,N) fp32 -> xh/xl bf16 split (same layout), xhT (B,N,C) bf16, sx row sums.
__global__ __launch_bounds__(256) void split_transpose(
    const float* __restrict__ x, u16* __restrict__ xh, u16* __restrict__ xl,
    u16* __restrict__ xhT, float* __restrict__ sx) {
  __shared__ u16 tile[64][66];
  int b = blockIdx.z, ct = blockIdx.y, nt = blockIdx.x;
  int lane = threadIdx.x & 63, w = threadIdx.x >> 6;
  const float* xb = x + ((size_t)b * C_ + ct * 64) * N_ + (size_t)nt * 64;
  for (int it = 0; it < 16; ++it) {
    int rl = it * 4 + w;  // local channel
    float v = xb[(size_t)rl * N_ + lane];
    u16 h = f2bf(v);
    u16 l = f2bf(v - bf2f(h));
    size_t go = ((size_t)b * C_ + ct * 64 + rl) * N_ + (size_t)nt * 64 + lane;
    xh[go] = h;
    xl[go] = l;
    tile[rl][lane] = h;
    float s = v;
    for (int o = 32; o; o >>= 1) s += __shfl_down(s, o);
    if (lane == 0) atomicAdd(&sx[b * C_ + ct * 64 + rl], s);
  }
  __syncthreads();
  for (int it = 0; it < 16; ++it) {
    int rl = it * 4 + w;  // local n
    xhT[((size_t)b * N_ + nt * 64 + rl) * C_ + ct * 64 + lane] = tile[lane][rl];
  }
}

// wq,wk -> bf16 hi/lo splits; wv -> wvT bf16 (transposed).
__global__ __launch_bounds__(256) void prep_weights(
    const float* __restrict__ wq, const float* __restrict__ wk, const float* __restrict__ wv,
    u16* __restrict__ wqh, u16* __restrict__ wql, u16* __restrict__ wkh,
    u16* __restrict__ wkl, u16* __restrict__ wvT) {
  int idx = blockIdx.x * 256 + threadIdx.x;
  float q = wq[idx];
  u16 qh = f2bf(q);
  wqh[idx] = qh;
  wql[idx] = f2bf(q - bf2f(qh));
  float k = wk[idx];
  u16 kh = f2bf(k);
  wkh[idx] = kh;
  wkl[idx] = f2bf(k - bf2f(kh));
  float v = wv[idx];
  wvT[(size_t)(idx & 511) * C_ + (idx >> 9)] = f2bf(v);
}

// aq[b,i] = sum_c wq[i,c] sx[b,c];  ak[b,j] = sum_c wk[j,c] sx[b,c]
__global__ __launch_bounds__(256) void bias_vec(
    const float* __restrict__ wq, const float* __restrict__ wk,
    const float* __restrict__ sx, float* __restrict__ aq, float* __restrict__ ak) {
  int gw = blockIdx.x * 4 + (threadIdx.x >> 6);  // 0..8191
  int lane = threadIdx.x & 63;
  int which = gw >> 12;
  int b = (gw >> 9) & 7, i = gw & 511;
  const float* wrow = (which ? wk : wq) + (size_t)i * C_;
  const float* sxb = sx + b * C_;
  float s = 0.f;
  for (int c = lane; c < C_; c += 64) s += wrow[c] * sxb[c];
  for (int o = 32; o; o >>= 1) s += __shfl_down(s, o);
  if (lane == 0) (which ? ak : aq)[b * C_ + i] = s;
}

// one wave per row: add bias terms, softmax, emit attn bf16 + obias = attn.bv
__global__ __launch_bounds__(256) void softmax_rows(
    const float* __restrict__ Sraw, const float* __restrict__ aq,
    const float* __restrict__ ak, const float* __restrict__ bq,
    const float* __restrict__ bk, const float* __restrict__ bv,
    u16* __restrict__ attn, float* __restrict__ obias) {
  int row = blockIdx.x * 4 + (threadIdx.x >> 6);  // b*512 + i
  int lane = threadIdx.x & 63;
  int b = row >> 9, i = row & 511;
  const float* srow = Sraw + (size_t)row * C_;
  const float* akb = ak + b * C_;
  float aqi = aq[row], bqi = bq[i];
  float lv[8], ev[8];
  float m = -3.4e38f;
  for (int t = 0; t < 8; ++t) {
    int j = t * 64 + lane;
    float v = srow[j] + aqi * bk[j] + bqi * (akb[j] + 4096.0f * bk[j]);
    lv[t] = v;
    m = fmaxf(m, v);
  }
  for (int o = 32; o; o >>= 1) m = fmaxf(m, __shfl_xor(m, o));
  float se = 0.f, sb = 0.f;
  for (int t = 0; t < 8; ++t) {
    int j = t * 64 + lane;
    float e = expf(lv[t] - m);
    ev[t] = e;
    se += e;
    sb += e * bv[j];
  }
  for (int o = 32; o; o >>= 1) {
    se += __shfl_xor(se, o);
    sb += __shfl_xor(sb, o);
  }
  float inv = 1.0f / se;
  for (int t = 0; t < 8; ++t) attn[(size_t)row * C_ + t * 64 + lane] = f2bf(ev[t] * inv);
  if (lane == 0) obias[row] = sb * inv;
}

extern "C" void kernel_launch(void* const* d_in, const int* in_sizes, int n_in,
                              void* d_out, int out_size, void* d_ws, size_t ws_size,
                              hipStream_t stream) {
  const float* x = (const float*)d_in[0];
  const float* wq = (const float*)d_in[1];
  const float* bq = (const float*)d_in[2];
  const float* wk = (const float*)d_in[3];
  const float* bk = (const float*)d_in[4];
  const float* wv = (const float*)d_in[5];
  const float* bv = (const float*)d_in[6];
  float* out = (float*)d_out;

  const size_t XN = (size_t)B_ * C_ * N_;   // 16.78M elems
  const size_t CCt = (size_t)B_ * C_ * C_;  // 2.10M elems
  const size_t W2 = (size_t)C_ * C_;

  u16* XH = (u16*)d_ws;
  u16* XL = XH + XN;
  u16* XHT = XL + XN;
  u16* GH = XHT + XN;
  u16* GL = GH + CCt;
  u16* UH = GL + CCt;
  u16* UL = UH + CCt;
  float* SRAW = (float*)(UL + CCt);
  u16* ATTN = (u16*)(SRAW + CCt);
  u16* MH = ATTN + CCt;
  u16* WQH = MH + CCt;
  u16* WQL = WQH + W2;
  u16* WKH = WQL + W2;
  u16* WKL = WKH + W2;
  u16* WVT = WKL + W2;
  float* SX = (float*)(WVT + W2);
  float* AQ = SX + B_ * C_;
  float* AK = AQ + B_ * C_;
  float* OBIAS = AK + B_ * C_;

  hipMemsetAsync(SX, 0, B_ * C_ * sizeof(float), stream);
  prep_weights<<<W2 / 256, 256, 0, stream>>>(wq, wk, wv, WQH, WQL, WKH, WKL, WVT);
  split_transpose<<<dim3(N_ / 64, C_ / 64, B_), 256, 0, stream>>>(x, XH, XL, XHT, SX);
  bias_vec<<<2048, 256, 0, stream>>>(wq, wk, SX, AQ, AK);

  // G = x x^T  (split store)
  gemm_bt<true, 1><<<dim3(4, 4, B_), 256, 0, stream>>>(
      XH, XL, (long long)((size_t)C_ * N_), XH, XL, (long long)((size_t)C_ * N_),
      N_, C_, nullptr, GH, GL, (long long)W2, nullptr);
  // U = wk G   (A = wk split, Bt = G split; G symmetric)
  gemm_bt<true, 1><<<dim3(4, 4, B_), 256, 0, stream>>>(
      WKH, WKL, 0, GH, GL, (long long)W2, C_, C_, nullptr, UH, UL, (long long)W2, nullptr);
  // S = wq U^T (fp32 store)
  gemm_bt<true, 0><<<dim3(4, 4, B_), 256, 0, stream>>>(
      WQH, WQL, 0, UH, UL, (long long)W2, C_, C_, SRAW, nullptr, nullptr, (long long)W2, nullptr);

  softmax_rows<<<(B_ * C_) / 4, 256, 0, stream>>>(SRAW, AQ, AK, bq, bk, bv, ATTN, OBIAS);

  // M = attn wv  (Bt = wv^T), bf16-hi store
  gemm_bt<false, 2><<<dim3(4, 4, B_), 256, 0, stream>>>(
      ATTN, nullptr, (long long)W2, WVT, nullptr, 0, C_, C_, nullptr, MH, nullptr,
      (long long)W2, nullptr);
  // out = M x + obias  (Bt = xh^T)
  gemm_bt<false, 3><<<dim3(N_ / 128, 4, B_), 256, 0, stream>>>(
      MH, nullptr, (long long)W2, XHT, nullptr, (long long)((size_t)N_ * C_), C_, N_,
      out, nullptr, nullptr, (long long)((size_t)C_ * N_), OBIAS);
}